// Round 1
// 151.599 us; speedup vs baseline: 1.0847x; 1.0847x over previous
//
#include <hip/hip_runtime.h>

#define H_ 4
#define N_ 1024
#define E_ 4096
#define LE_ 16384
#define FN_ 128
#define FE_ 64
#define HTN_ 16384   // node-pair hash slots (4x E)
#define HTE_ 65536   // line-pair hash slots (4x LE)
#define CAP_ 32      // per-source adjacency capacity (avg deg 4, P(>32) ~ 1e-18)

struct P {
  const float *Xn, *Xe;
  const int *src, *dst, *lgs, *lgd;
  const float *nqW, *nqb, *nkW, *nkb, *nvW, *nvb;
  const float *eqW, *eqb, *ekW, *ekb, *evW, *evb;
  const float *ncW, *ncb, *ecW, *ecb;
  float *out;
  float *NV, *EV, *nsa, *esa;
  int *hkN, *hvN, *hkE, *hvE;
  int *cntN, *cntE, *listN, *listE;
};

__device__ __forceinline__ unsigned hashN(int key) {
  return (((unsigned)key * 2654435761u) >> 16) & (HTN_ - 1);
}
__device__ __forceinline__ unsigned hashE(int key) {
  return (((unsigned)key * 2654435761u) >> 16) & (HTE_ - 1);
}

// ---------------------------------------------------------------------------
// One 64x64 GEMM tile: C[r0..+64, o0..+64] = [relu](X @ W^T + b).
// XOR-swizzled k-major LDS (verified R2/R3/R5/R6). 256 threads (ts in [0,256)).
// Barrier count: K=128 -> 8 syncthreads, K=64 -> 4.
// ---------------------------------------------------------------------------
template<int K, bool RELU>
__device__ void gemm_tile(const float* __restrict__ X, const float* __restrict__ W,
                          const float* __restrict__ b, float* __restrict__ C,
                          int O, int r0, int o0, float* smem, int t) {
  float* Xs = smem;
  float* Ws = smem + 2048;
  const int tn = t & 15, tm = t >> 4;
  float acc[4][4] = {};
  for (int k0 = 0; k0 < K; k0 += 32) {
#pragma unroll
    for (int ph = 0; ph < 2; ++ph) {
      int i4 = t + ph * 256;
      int m = i4 >> 3;
      int k4 = (i4 & 7) << 2;
      int m4 = m >> 2, ml = m & 3;
      float4 vx = *(const float4*)&X[(r0 + m) * K + k0 + k4];
      float4 vw = *(const float4*)&W[(o0 + m) * K + k0 + k4];
      Xs[(k4 + 0) * 64 + ((m4 ^ ((k4 + 0) & 15)) << 2) + ml] = vx.x;
      Xs[(k4 + 1) * 64 + ((m4 ^ ((k4 + 1) & 15)) << 2) + ml] = vx.y;
      Xs[(k4 + 2) * 64 + ((m4 ^ ((k4 + 2) & 15)) << 2) + ml] = vx.z;
      Xs[(k4 + 3) * 64 + ((m4 ^ ((k4 + 3) & 15)) << 2) + ml] = vx.w;
      Ws[(k4 + 0) * 64 + ((m4 ^ ((k4 + 0) & 15)) << 2) + ml] = vw.x;
      Ws[(k4 + 1) * 64 + ((m4 ^ ((k4 + 1) & 15)) << 2) + ml] = vw.y;
      Ws[(k4 + 2) * 64 + ((m4 ^ ((k4 + 2) & 15)) << 2) + ml] = vw.z;
      Ws[(k4 + 3) * 64 + ((m4 ^ ((k4 + 3) & 15)) << 2) + ml] = vw.w;
    }
    __syncthreads();
#pragma unroll
    for (int k = 0; k < 32; ++k) {
      float4 a = *(const float4*)&Xs[k * 64 + ((tm ^ (k & 15)) << 2)];
      float4 b4 = *(const float4*)&Ws[k * 64 + ((tn ^ (k & 15)) << 2)];
      acc[0][0] += a.x * b4.x; acc[0][1] += a.x * b4.y; acc[0][2] += a.x * b4.z; acc[0][3] += a.x * b4.w;
      acc[1][0] += a.y * b4.x; acc[1][1] += a.y * b4.y; acc[1][2] += a.y * b4.z; acc[1][3] += a.y * b4.w;
      acc[2][0] += a.z * b4.x; acc[2][1] += a.z * b4.y; acc[2][2] += a.z * b4.z; acc[2][3] += a.z * b4.w;
      acc[3][0] += a.w * b4.x; acc[3][1] += a.w * b4.y; acc[3][2] += a.w * b4.z; acc[3][3] += a.w * b4.w;
    }
    __syncthreads();
  }
  float4 bv = *(const float4*)&b[o0 + tn * 4];
#pragma unroll
  for (int i = 0; i < 4; ++i) {
    float4 o;
    o.x = acc[i][0] + bv.x; o.y = acc[i][1] + bv.y;
    o.z = acc[i][2] + bv.z; o.w = acc[i][3] + bv.w;
    if (RELU) {
      o.x = fmaxf(o.x, 0.f); o.y = fmaxf(o.y, 0.f);
      o.z = fmaxf(o.z, 0.f); o.w = fmaxf(o.w, 0.f);
    }
    *(float4*)&C[(r0 + tm * 4 + i) * O + o0 + tn * 4] = o;
  }
}

// ---------------------------------------------------------------------------
// kA: EVERYTHING independent + attention. Grid 124 x 1024.
//   blocks 0..3   : node attention heads (NK computed into LDS)
//   blocks 4..7   : edge attention heads (EK computed into LDS)
//   blocks 8..27  : hash inserts (E + LE = 20480 lanes)
//   blocks 28..123: NV/EV GEMM tiles, 4 x 256-thread groups per block.
//                   gg%3==0 -> NV tile (8 barriers), else EV tile (4+4 pad).
//                   Waves never straddle groups; barrier counts equal per block.
// ---------------------------------------------------------------------------
__global__ __launch_bounds__(1024) void kA(P p) {
  __shared__ float smem[16384];   // 64 KB: 4x 16KB GEMM groups / attn scratch
  const int tid = threadIdx.x;
  const int bid = blockIdx.x;

  if (bid >= 28) {   // ---------------- V GEMM tiles ----------------
    const int gg = (bid - 28) * 4 + (tid >> 8);   // 0..383
    const int ts_ = tid & 255;
    float* gsm = smem + (tid >> 8) * 4096;
    if (gg % 3 == 0) {
      const int tile = gg / 3;                    // 128 NV tiles, K=128
      gemm_tile<128, false>(p.Xn, p.nvW, p.nvb, p.NV, 512,
                            (tile >> 3) * 64, (tile & 7) * 64, gsm, ts_);
    } else {
      const int tile = gg - gg / 3 - 1;           // 256 EV tiles, K=64
      gemm_tile<64, false>(p.Xe, p.evW, p.evb, p.EV, 256,
                           (tile >> 2) * 64, (tile & 3) * 64, gsm, ts_);
      __syncthreads(); __syncthreads(); __syncthreads(); __syncthreads();
    }
    return;
  }

  if (bid >= 8) {    // ---------------- hash inserts ----------------
    int idx = (bid - 8) * 1024 + tid;
    if (idx < E_) {
      int key = p.src[idx] * N_ + p.dst[idx];
      unsigned slot = hashN(key);
      while (true) {
        int prev = atomicCAS(&p.hkN[slot], -1, key);
        if (prev == -1 || prev == key) break;
        slot = (slot + 1) & (HTN_ - 1);
      }
      atomicMax(&p.hvN[slot], idx);
    } else if (idx < E_ + LE_) {
      int l = idx - E_;
      int key = p.lgs[l] * E_ + p.lgd[l];
      unsigned slot = hashE(key);
      while (true) {
        int prev = atomicCAS(&p.hkE[slot], -1, key);
        if (prev == -1 || prev == key) break;
        slot = (slot + 1) & (HTE_ - 1);
      }
      atomicMax(&p.hvE[slot], l);
    }
    return;
  }

  // ---------------- attention ----------------
  float4* accs = (float4*)smem;        // 4096 floats
  float* red = smem + 4096;            // 1024
  float* ys  = smem + 5120;            // 512
  float* ts  = smem + 5632;            // 128
  float* zs  = smem + 5760;            // 528
  float* ds  = smem + 6288;            // 4
  float* sig = smem + 6292;            // 4
  float* Ks  = smem + 6304;            // node: 1024, edge: 4096 (16B aligned)

  if (bid < 4) {
    // ---------------- node head ----------------
    const int h = bid;
    const int r0 = h * 256;
    float* wkw = Ks + 1024;            // nkW copy: 512 floats
    for (int i = tid; i < 512; i += 1024) wkw[i] = p.nkW[i];
    __syncthreads();
    {  // NK for this head's 256 rows: one (row,c) dot per thread
      const int rl = tid >> 2, c = tid & 3;
      const float4* x4 = (const float4*)(p.Xn + (r0 + rl) * FN_);
      const float4* w4 = (const float4*)(wkw + c * FN_);
      float acc = p.nkb[c];
      for (int k = 0; k < 32; ++k) {
        float4 x = x4[k], w = w4[k];
        acc += x.x * w.x + x.y * w.y + x.z * w.z + x.w * w.w;
      }
      Ks[tid] = acc;                   // tid = rl*4 + c
    }
    __syncthreads();
    {
      int g = tid & 127, q = tid >> 7;      // 8 chunks x 32 rows
      const float4* Ks4 = (const float4*)Ks;
      float a0 = 0, a1 = 0, a2 = 0, a3 = 0;
      for (int jj = 0; jj < 32; ++jj) {
        int lr = q * 32 + jj;
        float x = p.Xn[(r0 + lr) * FN_ + g];
        float4 k = Ks4[lr];
        a0 += x * k.x; a1 += x * k.y; a2 += x * k.z; a3 += x * k.w;
      }
      accs[tid] = make_float4(a0, a1, a2, a3);
    }
    __syncthreads();
    for (int off = 512; off >= 128; off >>= 1) {
      if (tid < off) {
        float4 a = accs[tid], b = accs[tid + off];
        accs[tid] = make_float4(a.x + b.x, a.y + b.y, a.z + b.z, a.w + b.w);
      }
      __syncthreads();
    }
    if (tid < 128) {
      float4 a = accs[tid];
      ys[tid * 4 + 0] = a.x; ys[tid * 4 + 1] = a.y;
      ys[tid * 4 + 2] = a.z; ys[tid * 4 + 3] = a.w;
    }
    if (tid >= 128 && tid < 160) {
      int t2 = tid - 128, c = t2 & 3, part = t2 >> 2;
      float s = 0.f;
      for (int j = 0; j < 32; ++j) s += Ks[(part * 32 + j) * 4 + c];
      red[t2] = s;
    }
    __syncthreads();
    if (tid < 4) { float s = 0.f; for (int q = 0; q < 8; ++q) s += red[q * 4 + tid]; sig[tid] = s; }
    __syncthreads();
    if (tid < 512) {   // t[f] partials: row tid = c*128+f of nqW
      const float4* w4 = (const float4*)(p.nqW + tid * FN_);
      int c = tid >> 7;
      float s = 0.f;
      for (int g4 = 0; g4 < 32; ++g4) {
        float4 w = w4[g4];
        s += w.x * ys[(g4 * 4 + 0) * 4 + c] + w.y * ys[(g4 * 4 + 1) * 4 + c]
           + w.z * ys[(g4 * 4 + 2) * 4 + c] + w.w * ys[(g4 * 4 + 3) * 4 + c];
      }
      red[tid] = s;
    }
    __syncthreads();
    if (tid < 128) {
      float s = red[tid] + red[128 + tid] + red[256 + tid] + red[384 + tid];
      float bb = 0.f;
      for (int c = 0; c < 4; ++c) bb += p.nqb[c * 128 + tid] * sig[c];
      ts[tid] = s + bb;
    }
    __syncthreads();
    if (tid < 512) {   // z: c = tid>>7, g = tid&127
      int c = tid >> 7, g = tid & 127;
      float s = 0.f;
      for (int f = 0; f < 128; ++f) s += p.nqW[(c * 128 + f) * 128 + g] * ts[f];
      zs[c * 132 + g] = s;
    }
    if (tid >= 512 && tid < 516) {
      int c = tid - 512;
      float s = 0.f;
      for (int f = 0; f < 128; ++f) s += p.nqb[c * 128 + f] * ts[f];
      ds[c] = s;
    }
    __syncthreads();
    float sc;
    {   // scores: thread = position i = 4j+c
      int c = tid & 3, j = tid >> 2;
      const float4* x4 = (const float4*)(p.Xn + (r0 + j) * FN_);
      const float* z = zs + c * 132;
      float s = ds[c];
      for (int g4 = 0; g4 < 32; ++g4) {
        float4 x = x4[g4];
        s += x.x * z[g4 * 4] + x.y * z[g4 * 4 + 1] + x.z * z[g4 * 4 + 2] + x.w * z[g4 * 4 + 3];
      }
      sc = s;
    }
    red[tid] = sc;
    __syncthreads();
    for (int off = 512; off > 0; off >>= 1) {
      if (tid < off) red[tid] = fmaxf(red[tid], red[tid + off]);
      __syncthreads();
    }
    float m = red[0];
    __syncthreads();
    float e = expf(sc - m);
    red[tid] = e;
    __syncthreads();
    for (int off = 512; off > 0; off >>= 1) {
      if (tid < off) red[tid] += red[tid + off];
      __syncthreads();
    }
    p.nsa[h * N_ + tid] = e / red[0];
  } else {
    // ---------------- edge head ----------------
    const int h = bid - 4;
    const int r0 = h * 1024;
    float* wkw = Ks + 4096;            // ekW copy: 256 floats
    for (int i = tid; i < 256; i += 1024) wkw[i] = p.ekW[i];
    __syncthreads();
    {  // EK for this head's 1024 rows: one row per thread, all 4 c's
      const float4* x4 = (const float4*)(p.Xe + (r0 + tid) * FE_);
      const float4* w0 = (const float4*)wkw;
      const float4* w1 = (const float4*)(wkw + 64);
      const float4* w2 = (const float4*)(wkw + 128);
      const float4* w3 = (const float4*)(wkw + 192);
      float a0 = p.ekb[0], a1 = p.ekb[1], a2 = p.ekb[2], a3 = p.ekb[3];
      for (int k = 0; k < 16; ++k) {
        float4 x = x4[k];
        float4 u0 = w0[k], u1 = w1[k], u2 = w2[k], u3 = w3[k];
        a0 += x.x * u0.x + x.y * u0.y + x.z * u0.z + x.w * u0.w;
        a1 += x.x * u1.x + x.y * u1.y + x.z * u1.z + x.w * u1.w;
        a2 += x.x * u2.x + x.y * u2.y + x.z * u2.z + x.w * u2.w;
        a3 += x.x * u3.x + x.y * u3.y + x.z * u3.z + x.w * u3.w;
      }
      Ks[tid * 4 + 0] = a0; Ks[tid * 4 + 1] = a1;
      Ks[tid * 4 + 2] = a2; Ks[tid * 4 + 3] = a3;
    }
    __syncthreads();
    {
      int g = tid & 63, q = tid >> 6;      // 16 chunks x 64 rows
      const float4* Ks4 = (const float4*)Ks;
      float a0 = 0, a1 = 0, a2 = 0, a3 = 0;
      for (int jj = 0; jj < 64; ++jj) {
        int lr = q * 64 + jj;
        float x = p.Xe[(r0 + lr) * FE_ + g];
        float4 k = Ks4[lr];
        a0 += x * k.x; a1 += x * k.y; a2 += x * k.z; a3 += x * k.w;
      }
      accs[tid] = make_float4(a0, a1, a2, a3);
    }
    __syncthreads();
    for (int off = 512; off >= 64; off >>= 1) {
      if (tid < off) {
        float4 a = accs[tid], b = accs[tid + off];
        accs[tid] = make_float4(a.x + b.x, a.y + b.y, a.z + b.z, a.w + b.w);
      }
      __syncthreads();
    }
    if (tid < 64) {
      float4 a = accs[tid];
      ys[tid * 4 + 0] = a.x; ys[tid * 4 + 1] = a.y;
      ys[tid * 4 + 2] = a.z; ys[tid * 4 + 3] = a.w;
    }
    if (tid >= 128 && tid < 160) {
      int t2 = tid - 128, c = t2 & 3, part = t2 >> 2;
      float s = 0.f;
      for (int j = 0; j < 128; ++j) s += Ks[(part * 128 + j) * 4 + c];
      red[t2] = s;
    }
    __syncthreads();
    if (tid < 4) { float s = 0.f; for (int q = 0; q < 8; ++q) s += red[q * 4 + tid]; sig[tid] = s; }
    __syncthreads();
    if (tid < 256) {   // t[f] partials: row tid = c*64+f of eqW
      const float4* w4 = (const float4*)(p.eqW + tid * FE_);
      int c = tid >> 6;
      float s = 0.f;
      for (int g4 = 0; g4 < 16; ++g4) {
        float4 w = w4[g4];
        s += w.x * ys[(g4 * 4 + 0) * 4 + c] + w.y * ys[(g4 * 4 + 1) * 4 + c]
           + w.z * ys[(g4 * 4 + 2) * 4 + c] + w.w * ys[(g4 * 4 + 3) * 4 + c];
      }
      red[tid] = s;
    }
    __syncthreads();
    if (tid < 64) {
      float s = red[tid] + red[64 + tid] + red[128 + tid] + red[192 + tid];
      float bb = 0.f;
      for (int c = 0; c < 4; ++c) bb += p.eqb[c * 64 + tid] * sig[c];
      ts[tid] = s + bb;
    }
    __syncthreads();
    if (tid < 256) {   // z: c = tid>>6, g = tid&63
      int c = tid >> 6, g = tid & 63;
      float s = 0.f;
      for (int f = 0; f < 64; ++f) s += p.eqW[(c * 64 + f) * 64 + g] * ts[f];
      zs[c * 132 + g] = s;
    }
    if (tid >= 256 && tid < 260) {
      int c = tid - 256;
      float s = 0.f;
      for (int f = 0; f < 64; ++f) s += p.eqb[c * 64 + f] * ts[f];
      ds[c] = s;
    }
    __syncthreads();
    float s4[4];
    {   // scores: thread j handles positions 4j..4j+3 (one Xe row)
      const float4* x4 = (const float4*)(p.Xe + (r0 + tid) * FE_);
      s4[0] = ds[0]; s4[1] = ds[1]; s4[2] = ds[2]; s4[3] = ds[3];
      for (int g4 = 0; g4 < 16; ++g4) {
        float4 x = x4[g4];
#pragma unroll
        for (int c = 0; c < 4; ++c) {
          const float* z = zs + c * 132 + g4 * 4;
          s4[c] += x.x * z[0] + x.y * z[1] + x.z * z[2] + x.w * z[3];
        }
      }
    }
    float lm = fmaxf(fmaxf(s4[0], s4[1]), fmaxf(s4[2], s4[3]));
    red[tid] = lm;
    __syncthreads();
    for (int off = 512; off > 0; off >>= 1) {
      if (tid < off) red[tid] = fmaxf(red[tid], red[tid + off]);
      __syncthreads();
    }
    float m = red[0];
    __syncthreads();
    float e0 = expf(s4[0] - m), e1 = expf(s4[1] - m);
    float e2 = expf(s4[2] - m), e3 = expf(s4[3] - m);
    red[tid] = e0 + e1 + e2 + e3;
    __syncthreads();
    for (int off = 512; off > 0; off >>= 1) {
      if (tid < off) red[tid] += red[tid + off];
      __syncthreads();
    }
    float inv = 1.f / red[0];
    ((float4*)(p.esa + h * E_))[tid] = make_float4(e0 * inv, e1 * inv, e2 * inv, e3 * inv);
  }
}

// ---------------------------------------------------------------------------
// kB: build winner adjacency lists. Grid 80 x 256 = E + LE lanes.
// ---------------------------------------------------------------------------
__global__ __launch_bounds__(256) void kB(P p) {
  int idx = blockIdx.x * 256 + threadIdx.x;
  if (idx < E_) {
    int e = idx;
    int s = p.src[e], d = p.dst[e];
    int key = s * N_ + d;
    unsigned slot = hashN(key);
    while (p.hkN[slot] != key) slot = (slot + 1) & (HTN_ - 1);
    if (p.hvN[slot] != e) return;
    int pos = atomicAdd(&p.cntN[s], 1) & (CAP_ - 1);
    p.listN[s * CAP_ + pos] = (d << 12) | e;
  } else {
    int l = idx - E_;
    int j = p.lgs[l], c = p.lgd[l];
    int key = j * E_ + c;
    unsigned slot = hashE(key);
    while (p.hkE[slot] != key) slot = (slot + 1) & (HTE_ - 1);
    if (p.hvE[slot] != l) return;
    int pos = atomicAdd(&p.cntE[j], 1) & (CAP_ - 1);
    p.listE[j * CAP_ + pos] = c;
  }
}

// ---------------------------------------------------------------------------
// kC: gather fused with output GEMM. The gathered A-tile lands directly in
// swizzled k-major LDS (nagg/eagg eliminated). Grid 384 x 256:
//   blocks 0..127 : node out, tile rows = (h, 64 positions), col half o0.
//   blocks 128..383: edge out, tile rows = (h, 64 line-edges), 64 cols.
// ---------------------------------------------------------------------------
__global__ __launch_bounds__(256) void kC(P p) {
  __shared__ float smem[10240];  // node: Xs 8192 + Ws 2048; edge: Xs 4096 + Ws
  const int t = threadIdx.x, bid = blockIdx.x;
  float* Xs = smem;
  float* Ws = smem + 8192;
  const int tn = t & 15, tm = t >> 4;

  if (bid < 128) {
    // ---------------- node out ----------------
    const int rt = bid >> 1, o0 = (bid & 1) << 6;
    const int h = rt >> 4, p0 = (rt & 15) << 6;
    {
      const int m = t >> 2, q = t & 3;       // 4 threads per row; f4 = q+4f
      const int s = p0 + m;
      const int deg = min(p.cntN[s], CAP_);
      float4 acc[8];
#pragma unroll
      for (int f = 0; f < 8; ++f) acc[f] = make_float4(0.f, 0.f, 0.f, 0.f);
      const float4* NV4 = (const float4*)p.NV + (h << 15);
      const float* esah = p.esa + h * E_;
      for (int i = 0; i < deg; ++i) {
        int pk = p.listN[s * CAP_ + i];
        int e = pk & (E_ - 1), d = pk >> 12;
        float a = esah[e];
        const float4* v4 = NV4 + (d << 5);
#pragma unroll
        for (int f = 0; f < 8; ++f) {
          float4 v = v4[q + (f << 2)];
          acc[f].x += a * v.x; acc[f].y += a * v.y;
          acc[f].z += a * v.z; acc[f].w += a * v.w;
        }
      }
      const int m4 = m >> 2, ml = m & 3;
#pragma unroll
      for (int f = 0; f < 8; ++f) {
        int k4 = (q + (f << 2)) << 2;
        Xs[(k4 + 0) * 64 + ((m4 ^ ((k4 + 0) & 15)) << 2) + ml] = acc[f].x;
        Xs[(k4 + 1) * 64 + ((m4 ^ ((k4 + 1) & 15)) << 2) + ml] = acc[f].y;
        Xs[(k4 + 2) * 64 + ((m4 ^ ((k4 + 2) & 15)) << 2) + ml] = acc[f].z;
        Xs[(k4 + 3) * 64 + ((m4 ^ ((k4 + 3) & 15)) << 2) + ml] = acc[f].w;
      }
    }
    float c16[4][4] = {};
    for (int k0 = 0; k0 < 128; k0 += 32) {
#pragma unroll
      for (int ph = 0; ph < 2; ++ph) {
        int i4 = t + ph * 256;
        int mw = i4 >> 3, k4 = (i4 & 7) << 2;
        int w4i = mw >> 2, wl = mw & 3;
        float4 vw = *(const float4*)&p.ncW[(o0 + mw) * 128 + k0 + k4];
        Ws[(k4 + 0) * 64 + ((w4i ^ ((k4 + 0) & 15)) << 2) + wl] = vw.x;
        Ws[(k4 + 1) * 64 + ((w4i ^ ((k4 + 1) & 15)) << 2) + wl] = vw.y;
        Ws[(k4 + 2) * 64 + ((w4i ^ ((k4 + 2) & 15)) << 2) + wl] = vw.z;
        Ws[(k4 + 3) * 64 + ((w4i ^ ((k4 + 3) & 15)) << 2) + wl] = vw.w;
      }
      __syncthreads();
#pragma unroll
      for (int kk = 0; kk < 32; ++kk) {
        int k = k0 + kk;
        float4 a = *(const float4*)&Xs[k * 64 + ((tm ^ (k & 15)) << 2)];
        float4 b4 = *(const float4*)&Ws[kk * 64 + ((tn ^ (kk & 15)) << 2)];
        c16[0][0] += a.x * b4.x; c16[0][1] += a.x * b4.y; c16[0][2] += a.x * b4.z; c16[0][3] += a.x * b4.w;
        c16[1][0] += a.y * b4.x; c16[1][1] += a.y * b4.y; c16[1][2] += a.y * b4.z; c16[1][3] += a.y * b4.w;
        c16[2][0] += a.z * b4.x; c16[2][1] += a.z * b4.y; c16[2][2] += a.z * b4.z; c16[2][3] += a.z * b4.w;
        c16[3][0] += a.w * b4.x; c16[3][1] += a.w * b4.y; c16[3][2] += a.w * b4.z; c16[3][3] += a.w * b4.w;
      }
      __syncthreads();
    }
    float4 bv = *(const float4*)&p.ncb[o0 + tn * 4];
#pragma unroll
    for (int i = 0; i < 4; ++i) {
      float4 o;
      o.x = fmaxf(c16[i][0] + bv.x, 0.f); o.y = fmaxf(c16[i][1] + bv.y, 0.f);
      o.z = fmaxf(c16[i][2] + bv.z, 0.f); o.w = fmaxf(c16[i][3] + bv.w, 0.f);
      *(float4*)&p.out[((h << 10) + p0 + tm * 4 + i) * 128 + o0 + tn * 4] = o;
    }
  } else {
    // ---------------- edge out ----------------
    const int rt = bid - 128;
    const int h = rt >> 6, j0 = (rt & 63) << 6;
    {
      const int m = t >> 2, q = t & 3;       // f4 = q+4f, f<4
      const int j = j0 + m;
      const int deg = min(p.cntE[j], CAP_);
      float4 acc[4];
#pragma unroll
      for (int f = 0; f < 4; ++f) acc[f] = make_float4(0.f, 0.f, 0.f, 0.f);
      const float4* EV4 = (const float4*)p.EV + (h << 16);
      for (int i = 0; i < deg; ++i) {
        int c = p.listE[j * CAP_ + i];
        const float4* v4 = EV4 + (c << 4);
#pragma unroll
        for (int f = 0; f < 4; ++f) {
          float4 v = v4[q + (f << 2)];
          acc[f].x += v.x; acc[f].y += v.y; acc[f].z += v.z; acc[f].w += v.w;
        }
      }
      float a = p.nsa[h * N_ + p.dst[j]];
      const int m4 = m >> 2, ml = m & 3;
#pragma unroll
      for (int f = 0; f < 4; ++f) {
        int k4 = (q + (f << 2)) << 2;
        Xs[(k4 + 0) * 64 + ((m4 ^ ((k4 + 0) & 15)) << 2) + ml] = a * acc[f].x;
        Xs[(k4 + 1) * 64 + ((m4 ^ ((k4 + 1) & 15)) << 2) + ml] = a * acc[f].y;
        Xs[(k4 + 2) * 64 + ((m4 ^ ((k4 + 2) & 15)) << 2) + ml] = a * acc[f].z;
        Xs[(k4 + 3) * 64 + ((m4 ^ ((k4 + 3) & 15)) << 2) + ml] = a * acc[f].w;
      }
    }
    float c16[4][4] = {};
    for (int k0 = 0; k0 < 64; k0 += 32) {
#pragma unroll
      for (int ph = 0; ph < 2; ++ph) {
        int i4 = t + ph * 256;
        int mw = i4 >> 3, k4 = (i4 & 7) << 2;
        int w4i = mw >> 2, wl = mw & 3;
        float4 vw = *(const float4*)&p.ecW[mw * 64 + k0 + k4];
        Ws[(k4 + 0) * 64 + ((w4i ^ ((k4 + 0) & 15)) << 2) + wl] = vw.x;
        Ws[(k4 + 1) * 64 + ((w4i ^ ((k4 + 1) & 15)) << 2) + wl] = vw.y;
        Ws[(k4 + 2) * 64 + ((w4i ^ ((k4 + 2) & 15)) << 2) + wl] = vw.z;
        Ws[(k4 + 3) * 64 + ((w4i ^ ((k4 + 3) & 15)) << 2) + wl] = vw.w;
      }
      __syncthreads();
#pragma unroll
      for (int kk = 0; kk < 32; ++kk) {
        int k = k0 + kk;
        float4 a = *(const float4*)&Xs[k * 64 + ((tm ^ (k & 15)) << 2)];
        float4 b4 = *(const float4*)&Ws[kk * 64 + ((tn ^ (kk & 15)) << 2)];
        c16[0][0] += a.x * b4.x; c16[0][1] += a.x * b4.y; c16[0][2] += a.x * b4.z; c16[0][3] += a.x * b4.w;
        c16[1][0] += a.y * b4.x; c16[1][1] += a.y * b4.y; c16[1][2] += a.y * b4.z; c16[1][3] += a.y * b4.w;
        c16[2][0] += a.z * b4.x; c16[2][1] += a.z * b4.y; c16[2][2] += a.z * b4.z; c16[2][3] += a.z * b4.w;
        c16[3][0] += a.w * b4.x; c16[3][1] += a.w * b4.y; c16[3][2] += a.w * b4.z; c16[3][3] += a.w * b4.w;
      }
      __syncthreads();
    }
    float4 bv = *(const float4*)&p.ecb[tn * 4];
    float* out2 = p.out + 524288;   // H_*N_*128
#pragma unroll
    for (int i = 0; i < 4; ++i) {
      float4 o;
      o.x = fmaxf(c16[i][0] + bv.x, 0.f); o.y = fmaxf(c16[i][1] + bv.y, 0.f);
      o.z = fmaxf(c16[i][2] + bv.z, 0.f); o.w = fmaxf(c16[i][3] + bv.w, 0.f);
      *(float4*)&out2[((h << 12) + j0 + tm * 4 + i) * 64 + tn * 4] = o;
    }
  }
}

// ---------------------------------------------------------------------------
extern "C" void kernel_launch(void* const* d_in, const int* in_sizes, int n_in,
                              void* d_out, int out_size, void* d_ws, size_t ws_size,
                              hipStream_t stream) {
  P p;
  p.Xn  = (const float*)d_in[0];
  p.Xe  = (const float*)d_in[1];
  p.src = (const int*)d_in[2];
  p.dst = (const int*)d_in[3];
  p.lgs = (const int*)d_in[4];
  p.lgd = (const int*)d_in[5];
  p.nqW = (const float*)d_in[6];  p.nqb = (const float*)d_in[7];
  p.nkW = (const float*)d_in[8];  p.nkb = (const float*)d_in[9];
  p.nvW = (const float*)d_in[10]; p.nvb = (const float*)d_in[11];
  p.eqW = (const float*)d_in[12]; p.eqb = (const float*)d_in[13];
  p.ekW = (const float*)d_in[14]; p.ekb = (const float*)d_in[15];
  p.evW = (const float*)d_in[16]; p.evb = (const float*)d_in[17];
  p.ncW = (const float*)d_in[18]; p.ncb = (const float*)d_in[19];
  p.ecW = (const float*)d_in[20]; p.ecb = (const float*)d_in[21];
  p.out = (float*)d_out;

  float* f = (float*)d_ws;
  p.NV   = f; f += N_ * H_ * FN_;   // 524288
  p.EV   = f; f += E_ * H_ * FE_;   // 1048576
  p.nsa  = f; f += H_ * N_;         // 4096
  p.esa  = f; f += H_ * E_;         // 16384
  int* ip = (int*)f;
  p.hkN  = ip; ip += HTN_;          // hash region contiguous
  p.hvN  = ip; ip += HTN_;
  p.hkE  = ip; ip += HTE_;
  p.hvE  = ip; ip += HTE_;
  p.cntN = ip; ip += N_;            // counters contiguous
  p.cntE = ip; ip += E_;
  p.listN = ip; ip += N_ * CAP_;
  p.listE = ip; ip += E_ * CAP_;

  // hash init to -1 (0xFF bytes), counters to 0 — replaces the init kernel
  hipMemsetAsync(p.hkN, 0xFF, (size_t)(2 * HTN_ + 2 * HTE_) * sizeof(int), stream);
  hipMemsetAsync(p.cntN, 0, (size_t)(N_ + E_) * sizeof(int), stream);

  kA<<<124, 1024, 0, stream>>>(p);   // attn + inserts + NV/EV GEMMs
  kB<<<80, 256, 0, stream>>>(p);     // winner lists
  kC<<<384, 256, 0, stream>>>(p);    // gather fused with output GEMMs
}